// Round 1
// baseline (679.989 us; speedup 1.0000x reference)
//
#include <hip/hip_runtime.h>

#define LVLS  16
#define TSZ   524288u          // 2^19
#define TMASK (TSZ - 1u)
#define PRIME 2654435761u
#define WIDTH 64
#define FIN   32               // L*F
#define NOUT  3

__global__ __launch_bounds__(256) void ngp_fused(
    const float* __restrict__ x,
    const float* __restrict__ tables,
    const float* __restrict__ W0, const float* __restrict__ b0,
    const float* __restrict__ W1, const float* __restrict__ b1,
    const float* __restrict__ W2, const float* __restrict__ b2,
    float* __restrict__ out, int N)
{
    __shared__ float sW0[FIN * WIDTH];     // 32x64
    __shared__ float sW1[WIDTH * WIDTH];   // 64x64
    __shared__ float sW2[WIDTH * 4];       // 64x4 (padded from 64x3)
    __shared__ float sB0[WIDTH];
    __shared__ float sB1[WIDTH];
    __shared__ float sB2[4];

    const int tid = threadIdx.x;
    for (int i = tid; i < FIN * WIDTH; i += 256) sW0[i] = W0[i];
    for (int i = tid; i < WIDTH * WIDTH; i += 256) sW1[i] = W1[i];
    if (tid < WIDTH) {
        sB0[tid] = b0[tid];
        sB1[tid] = b1[tid];
        sW2[tid * 4 + 0] = W2[tid * 3 + 0];
        sW2[tid * 4 + 1] = W2[tid * 3 + 1];
        sW2[tid * 4 + 2] = W2[tid * 3 + 2];
        sW2[tid * 4 + 3] = 0.f;
    }
    if (tid < 4) sB2[tid] = (tid < 3) ? b2[tid] : 0.f;
    __syncthreads();

    const int n = blockIdx.x * 256 + tid;
    if (n >= N) return;

    const float2 xy = ((const float2*)x)[n];

    // floor(16 * g^l), g = 128^(1/15) — matches np float64 then float32 cast
    const float c_res[LVLS] = {16.f, 22.f, 30.f, 42.f, 58.f, 80.f, 111.f, 153.f,
                               212.f, 294.f, 406.f, 561.f, 776.f, 1072.f, 1482.f, 2048.f};

    float h0[FIN];
    #pragma unroll
    for (int l = 0; l < LVLS; ++l) {
        const float r = c_res[l];
        const float sx = xy.x * r, sy = xy.y * r;
        const float fx = floorf(sx), fy = floorf(sy);
        const float ux = sx - fx, uy = sy - fy;
        const unsigned ix = (unsigned)(int)fx;
        const unsigned iy = (unsigned)(int)fy;
        const unsigned hy0 = iy * PRIME;
        const unsigned hy1 = (iy + 1u) * PRIME;
        const unsigned i00 = (ix ^ hy0) & TMASK;
        const unsigned i10 = ((ix + 1u) ^ hy0) & TMASK;
        const unsigned i01 = (ix ^ hy1) & TMASK;
        const unsigned i11 = ((ix + 1u) ^ hy1) & TMASK;
        const float2* tb = (const float2*)(tables + (size_t)l * (TSZ * 2));
        const float2 f00 = tb[i00];
        const float2 f10 = tb[i10];
        const float2 f01 = tb[i01];
        const float2 f11 = tb[i11];
        const float w00 = (1.f - ux) * (1.f - uy);
        const float w10 = ux * (1.f - uy);
        const float w01 = (1.f - ux) * uy;
        const float w11 = ux * uy;
        h0[2 * l]     = w00 * f00.x + w10 * f10.x + w01 * f01.x + w11 * f11.x;
        h0[2 * l + 1] = w00 * f00.y + w10 * f10.y + w01 * f01.y + w11 * f11.y;
    }

    // ---- layer 0: 32 -> 64, ReLU ----
    float4 acc[16];
    #pragma unroll
    for (int j = 0; j < 16; ++j) acc[j] = ((const float4*)sB0)[j];
    #pragma unroll
    for (int i = 0; i < FIN; ++i) {
        const float v = h0[i];
        const float4* w = (const float4*)(sW0 + i * WIDTH);
        #pragma unroll
        for (int j = 0; j < 16; ++j) {
            const float4 ww = w[j];
            acc[j].x = fmaf(v, ww.x, acc[j].x);
            acc[j].y = fmaf(v, ww.y, acc[j].y);
            acc[j].z = fmaf(v, ww.z, acc[j].z);
            acc[j].w = fmaf(v, ww.w, acc[j].w);
        }
    }
    float h1[WIDTH];
    #pragma unroll
    for (int j = 0; j < 16; ++j) {
        h1[4 * j + 0] = fmaxf(acc[j].x, 0.f);
        h1[4 * j + 1] = fmaxf(acc[j].y, 0.f);
        h1[4 * j + 2] = fmaxf(acc[j].z, 0.f);
        h1[4 * j + 3] = fmaxf(acc[j].w, 0.f);
    }

    // ---- layer 1: 64 -> 64, ReLU ----
    #pragma unroll
    for (int j = 0; j < 16; ++j) acc[j] = ((const float4*)sB1)[j];
    #pragma unroll
    for (int i = 0; i < WIDTH; ++i) {
        const float v = h1[i];
        const float4* w = (const float4*)(sW1 + i * WIDTH);
        #pragma unroll
        for (int j = 0; j < 16; ++j) {
            const float4 ww = w[j];
            acc[j].x = fmaf(v, ww.x, acc[j].x);
            acc[j].y = fmaf(v, ww.y, acc[j].y);
            acc[j].z = fmaf(v, ww.z, acc[j].z);
            acc[j].w = fmaf(v, ww.w, acc[j].w);
        }
    }
    float h2[WIDTH];
    #pragma unroll
    for (int j = 0; j < 16; ++j) {
        h2[4 * j + 0] = fmaxf(acc[j].x, 0.f);
        h2[4 * j + 1] = fmaxf(acc[j].y, 0.f);
        h2[4 * j + 2] = fmaxf(acc[j].z, 0.f);
        h2[4 * j + 3] = fmaxf(acc[j].w, 0.f);
    }

    // ---- layer 2: 64 -> 3, sigmoid ----
    float o0 = sB2[0], o1 = sB2[1], o2 = sB2[2];
    #pragma unroll
    for (int i = 0; i < WIDTH; ++i) {
        const float4 w = ((const float4*)sW2)[i];
        const float v = h2[i];
        o0 = fmaf(v, w.x, o0);
        o1 = fmaf(v, w.y, o1);
        o2 = fmaf(v, w.z, o2);
    }
    o0 = 1.f / (1.f + __expf(-o0));
    o1 = 1.f / (1.f + __expf(-o1));
    o2 = 1.f / (1.f + __expf(-o2));

    out[(size_t)n * 3 + 0] = o0;
    out[(size_t)n * 3 + 1] = o1;
    out[(size_t)n * 3 + 2] = o2;
}

extern "C" void kernel_launch(void* const* d_in, const int* in_sizes, int n_in,
                              void* d_out, int out_size, void* d_ws, size_t ws_size,
                              hipStream_t stream) {
    const float* x      = (const float*)d_in[0];
    const float* tables = (const float*)d_in[1];
    const float* W0     = (const float*)d_in[2];
    const float* b0     = (const float*)d_in[3];
    const float* W1     = (const float*)d_in[4];
    const float* b1     = (const float*)d_in[5];
    const float* W2     = (const float*)d_in[6];
    const float* b2     = (const float*)d_in[7];
    float* out = (float*)d_out;

    const int N = in_sizes[0] / 2;
    const int grid = (N + 255) / 256;
    ngp_fused<<<grid, 256, 0, stream>>>(x, tables, W0, b0, W1, b1, W2, b2, out, N);
}